// Round 14
// baseline (445.542 us; speedup 1.0000x reference)
//
#include <hip/hip_runtime.h>
#include <math.h>

#define NN 100000
#define DD 128
#define CC 64
#define TT 8
#define NS 50000
#define G8 8
#define MAXS 196            // A strips/g: ceil(50000/256)
#define MAXS_B 98           // B strips/g: ceil(25000/256)
#define T1MAX (G8 * MAXS)   // 1568
#define T2MAX (G8 * MAXS_B) // 784
#define L2CAP 25000
#define ZINT4 200032        // (NN*8 + 128) ints / 4

typedef __attribute__((ext_vector_type(4))) float f32x4;
typedef __attribute__((ext_vector_type(8))) short bf16x8;
typedef unsigned short ushort_t;

__device__ __forceinline__ short f2bf(float f) {
    union { float f; unsigned u; } v; v.f = f;
    unsigned r = v.u + 0x7fffu + ((v.u >> 16) & 1u);
    return (short)(r >> 16);
}
__device__ __forceinline__ unsigned pk_bf16(float lo, float hi) {
    unsigned r;
    asm("v_cvt_pk_bf16_f32 %0, %1, %2" : "=v"(r) : "v"(lo), "v"(hi));
    return r;
}
// tanh-form GELU via hardware exp: max |diff| vs exact erf-GELU ~3e-3
__device__ __forceinline__ float gelu(float x) {
    float t = x + 0.044715f * x * x * x;
    return x / (1.0f + __expf(-1.5957691216f * t));
}

// ------- weights -> MFMA-fragment tables + zero pernode/cnts (one kernel) ----
__global__ void prep_all(const float* __restrict__ Wd1, const float* __restrict__ Wd2,
                         const float* __restrict__ Wu1, const float* __restrict__ Wu2,
                         short* __restrict__ pW1, short* __restrict__ pW2,
                         short* __restrict__ pW3, short* __restrict__ pW4,
                         int4* __restrict__ zbase) {
    int b = blockIdx.x;
    if (b >= 36) {
        int i = (b - 36) * 256 + threadIdx.x;
        if (i < ZINT4) zbase[i] = (int4){0, 0, 0, 0};
        return;
    }
    const float* W; short* dst; int KSTEPS, total, N, s0;
    if (b < 16)      { W = Wd1; dst = pW1; KSTEPS = 4; total = 4096; N = 256; s0 = b * 256; }
    else if (b < 24) { W = Wd2; dst = pW2; KSTEPS = 8; total = 2048; N = 64;  s0 = (b - 16) * 256; }
    else if (b < 28) { W = Wu1; dst = pW3; KSTEPS = 2; total = 1024; N = 128; s0 = (b - 24) * 256; }
    else             { W = Wu2; dst = pW4; KSTEPS = 4; total = 2048; N = 128; s0 = (b - 28) * 256; }
    int s = s0 + threadIdx.x;
    if (s >= total) return;
    int lane = s & 63;
    int ks = (s >> 6) % KSTEPS;
    int n = s / (64 * KSTEPS);
    int kb = ks * 32 + (lane >> 4) * 8;
    int col = n * 16 + (lane & 15);
    bf16x8 o;
    #pragma unroll
    for (int j = 0; j < 8; ++j) o[j] = f2bf(W[(size_t)(kb + j) * N + col]);
    *(bf16x8*)(dst + (size_t)s * 8) = o;
}

// -------- count + record contributor positions (packed u16 buckets) --------
__global__ void flagfill_kernel(const int* __restrict__ idx, int* __restrict__ pernode,
                                ushort_t* __restrict__ bucket) {
    int i = blockIdx.x * 256 + threadIdx.x;
    if (i >= G8 * NS) return;
    int g = i / NS, s = i - g * NS;
    int node = idx[i];
    int p = atomicAdd(&pernode[node * 8 + g], 1);
    if (p < 16) bucket[((size_t)node * 8 + g) * 16 + p] = (ushort_t)s;
}

// ------ list1: {pos,node} pairs with c==1; list2: nodes with c>=2 ----------
__global__ void compact2_kernel(const int* __restrict__ idx, const int* __restrict__ pernode,
                                int2* __restrict__ list1, int* __restrict__ cnts1,
                                int* __restrict__ list2, int* __restrict__ cnts2) {
    int g = blockIdx.y;
    int i = blockIdx.x * 256 + threadIdx.x;
    int lane = threadIdx.x & 63;
    bool a1 = false;
    int nd1 = 0;
    if (i < NS) {
        nd1 = idx[(size_t)g * NS + i];
        a1 = (pernode[nd1 * 8 + g] == 1);
    }
    unsigned long long m1 = __ballot(a1);
    int r1 = __popcll(m1 & ((1ull << lane) - 1ull));
    int c1 = __popcll(m1);
    int b1 = 0;
    if (lane == 0 && c1 > 0) b1 = atomicAdd(&cnts1[g], c1);
    b1 = __shfl(b1, 0);
    if (a1) list1[(size_t)g * NS + b1 + r1] = (int2){i, nd1};
    bool a2 = (i < NN) && (pernode[i * 8 + g] >= 2);
    unsigned long long m2 = __ballot(a2);
    int r2 = __popcll(m2 & ((1ull << lane) - 1ull));
    int c2 = __popcll(m2);
    int b2 = 0;
    if (lane == 0 && c2 > 0) b2 = atomicAdd(&cnts2[g], c2);
    b2 = __shfl(b2, 0);
    if (a2) list2[(size_t)g * L2CAP + b2 + r2] = i;
}

// ---- LN_d in A-fragment layout: v[32] -> afr[4]
__device__ __forceinline__ void ln_d_pack(
    const float (&v)[32], int kgrp,
    const float* __restrict__ lndg, const float* __restrict__ lndb, bf16x8 (&afr)[4]) {
    float s1 = 0.f;
    #pragma unroll
    for (int j = 0; j < 32; ++j) s1 += v[j];
    s1 += __shfl_xor(s1, 16); s1 += __shfl_xor(s1, 32);
    float mu = s1 * 0.0078125f;
    float s2 = 0.f;
    #pragma unroll
    for (int j = 0; j < 32; ++j) { float d = v[j] - mu; s2 += d * d; }
    s2 += __shfl_xor(s2, 16); s2 += __shfl_xor(s2, 32);
    float rs = rsqrtf(s2 * 0.0078125f + 1e-5f);
    union U8 { bf16x8 v8; unsigned u[4]; };
    const float* gp = lndg + kgrp * 8;
    const float* bbp = lndb + kgrp * 8;
    #pragma unroll
    for (int ks = 0; ks < 4; ++ks) {
        float4 g0 = *(const float4*)(gp + ks * 32);
        float4 g1 = *(const float4*)(gp + ks * 32 + 4);
        float4 c0 = *(const float4*)(bbp + ks * 32);
        float4 c1 = *(const float4*)(bbp + ks * 32 + 4);
        U8 t;
        t.u[0] = pk_bf16((v[ks*8+0]-mu)*rs*g0.x + c0.x, (v[ks*8+1]-mu)*rs*g0.y + c0.y);
        t.u[1] = pk_bf16((v[ks*8+2]-mu)*rs*g0.z + c0.z, (v[ks*8+3]-mu)*rs*g0.w + c0.w);
        t.u[2] = pk_bf16((v[ks*8+4]-mu)*rs*g1.x + c1.x, (v[ks*8+5]-mu)*rs*g1.y + c1.y);
        t.u[3] = pk_bf16((v[ks*8+6]-mu)*rs*g1.z + c1.z, (v[ks*8+7]-mu)*rs*g1.w + c1.w);
        afr[ks] = t.v8;
    }
}

// ---- dual MLP core: two independent sub-tiles interleaved; weight reads shared
__device__ __forceinline__ void mlp_core2(
    const bf16x8 (&afrA)[4], const bf16x8 (&afrB)[4],
    short* mybA, short* mybB, int arow, int kgrp,
    const short* sW1, const short* sW2, const short* __restrict__ pW3, const short* sW4,
    const float* __restrict__ bd1, const float* __restrict__ bd2,
    const float* __restrict__ lnug, const float* __restrict__ lnub,
    const float* __restrict__ bu1, f32x4 (&acc4A)[8], f32x4 (&acc4B)[8]) {
    const int lane = kgrp * 16 + arow;
    f32x4 acc2A[4], acc2B[4];
    #pragma unroll
    for (int n = 0; n < 4; ++n) {
        acc2A[n] = (f32x4){0.f, 0.f, 0.f, 0.f};
        acc2B[n] = (f32x4){0.f, 0.f, 0.f, 0.f};
    }
    for (int ks2 = 0; ks2 < 8; ++ks2) {
        f32x4 a1A[2], a1B[2];
        a1A[0] = (f32x4){0.f, 0.f, 0.f, 0.f}; a1A[1] = a1A[0];
        a1B[0] = a1A[0]; a1B[1] = a1A[0];
        #pragma unroll
        for (int ks1 = 0; ks1 < 4; ++ks1) {
            #pragma unroll
            for (int p = 0; p < 2; ++p) {
                bf16x8 bf = *(const bf16x8*)(sW1 + (size_t)((((2 * ks2 + p) << 2) | ks1) * 64 + lane) * 8);
                a1A[p] = __builtin_amdgcn_mfma_f32_16x16x32_bf16(afrA[ks1], bf, a1A[p], 0, 0, 0);
                a1B[p] = __builtin_amdgcn_mfma_f32_16x16x32_bf16(afrB[ks1], bf, a1B[p], 0, 0, 0);
            }
        }
        #pragma unroll
        for (int p = 0; p < 2; ++p) {
            float bias = bd1[(2 * ks2 + p) * 16 + arow];
            #pragma unroll
            for (int rr = 0; rr < 4; ++rr) {
                int row = kgrp * 4 + rr;
                int off = (row * 64 + (((p * 16 + arow) * 2) ^ ((row & 3) << 4))) >> 1;
                mybA[off] = f2bf(gelu(a1A[p][rr] + bias));
                mybB[off] = f2bf(gelu(a1B[p][rr] + bias));
            }
        }
        int roff = (arow * 64 + ((kgrp * 16) ^ ((arow & 3) << 4))) >> 1;
        bf16x8 af2A = *(const bf16x8*)(mybA + roff);
        bf16x8 af2B = *(const bf16x8*)(mybB + roff);
        #pragma unroll
        for (int n2 = 0; n2 < 4; ++n2) {
            bf16x8 bf = *(const bf16x8*)(sW2 + (size_t)(((n2 << 3) | ks2) * 64 + lane) * 8);
            acc2A[n2] = __builtin_amdgcn_mfma_f32_16x16x32_bf16(af2A, bf, acc2A[n2], 0, 0, 0);
            acc2B[n2] = __builtin_amdgcn_mfma_f32_16x16x32_bf16(af2B, bf, acc2B[n2], 0, 0, 0);
        }
    }
    // ---- + bd2, LN_u over C=64 (both sub-tiles, interleaved chains)
    float hvA[4][4], hvB[4][4];
    #pragma unroll
    for (int n2 = 0; n2 < 4; ++n2)
        #pragma unroll
        for (int rr = 0; rr < 4; ++rr) {
            float b2 = bd2[n2 * 16 + arow];
            hvA[n2][rr] = acc2A[n2][rr] + b2;
            hvB[n2][rr] = acc2B[n2][rr] + b2;
        }
    #pragma unroll
    for (int rr = 0; rr < 4; ++rr) {
        float srA = hvA[0][rr] + hvA[1][rr] + hvA[2][rr] + hvA[3][rr];
        float srB = hvB[0][rr] + hvB[1][rr] + hvB[2][rr] + hvB[3][rr];
        srA += __shfl_xor(srA, 1); srB += __shfl_xor(srB, 1);
        srA += __shfl_xor(srA, 2); srB += __shfl_xor(srB, 2);
        srA += __shfl_xor(srA, 4); srB += __shfl_xor(srB, 4);
        srA += __shfl_xor(srA, 8); srB += __shfl_xor(srB, 8);
        float muA = srA * 0.015625f, muB = srB * 0.015625f;
        float sqA = 0.f, sqB = 0.f;
        #pragma unroll
        for (int n2 = 0; n2 < 4; ++n2) {
            float dA = hvA[n2][rr] - muA; sqA += dA * dA;
            float dB = hvB[n2][rr] - muB; sqB += dB * dB;
        }
        sqA += __shfl_xor(sqA, 1); sqB += __shfl_xor(sqB, 1);
        sqA += __shfl_xor(sqA, 2); sqB += __shfl_xor(sqB, 2);
        sqA += __shfl_xor(sqA, 4); sqB += __shfl_xor(sqB, 4);
        sqA += __shfl_xor(sqA, 8); sqB += __shfl_xor(sqB, 8);
        float rsA = rsqrtf(sqA * 0.015625f + 1e-5f);
        float rsB = rsqrtf(sqB * 0.015625f + 1e-5f);
        #pragma unroll
        for (int n2 = 0; n2 < 4; ++n2) {
            int cidx = n2 * 16 + arow;
            float gg = lnug[cidx], bb = lnub[cidx];
            int row = kgrp * 4 + rr;
            int off = (row * 128 + ((cidx * 2) ^ ((row & 7) << 4))) >> 1;
            mybA[off] = f2bf((hvA[n2][rr] - muA) * rsA * gg + bb);
            mybB[off] = f2bf((hvB[n2][rr] - muB) * rsB * gg + bb);
        }
    }
    bf16x8 af3A[2], af3B[2];
    #pragma unroll
    for (int ks3 = 0; ks3 < 2; ++ks3) {
        int off = (arow * 128 + ((ks3 * 64 + kgrp * 16) ^ ((arow & 7) << 4))) >> 1;
        af3A[ks3] = *(const bf16x8*)(mybA + off);
        af3B[ks3] = *(const bf16x8*)(mybB + off);
    }
    // ---- GEMM3 (K=64 -> 128, B-frags from global/L2) + GELU + GEMM4
    #pragma unroll
    for (int n = 0; n < 8; ++n) {
        acc4A[n] = (f32x4){0.f, 0.f, 0.f, 0.f};
        acc4B[n] = (f32x4){0.f, 0.f, 0.f, 0.f};
    }
    #pragma unroll
    for (int half = 0; half < 2; ++half) {
        f32x4 a3A[4], a3B[4];
        #pragma unroll
        for (int n = 0; n < 4; ++n) {
            a3A[n] = (f32x4){0.f, 0.f, 0.f, 0.f};
            a3B[n] = (f32x4){0.f, 0.f, 0.f, 0.f};
        }
        #pragma unroll
        for (int ks3 = 0; ks3 < 2; ++ks3) {
            #pragma unroll
            for (int n3h = 0; n3h < 4; ++n3h) {
                int n3 = half * 4 + n3h;
                bf16x8 bf = *(const bf16x8*)(pW3 + (size_t)(((n3 << 1) | ks3) * 64 + lane) * 8);
                a3A[n3h] = __builtin_amdgcn_mfma_f32_16x16x32_bf16(af3A[ks3], bf, a3A[n3h], 0, 0, 0);
                a3B[n3h] = __builtin_amdgcn_mfma_f32_16x16x32_bf16(af3B[ks3], bf, a3B[n3h], 0, 0, 0);
            }
        }
        #pragma unroll
        for (int n3h = 0; n3h < 4; ++n3h) {
            float bias = bu1[(half * 4 + n3h) * 16 + arow];
            #pragma unroll
            for (int rr = 0; rr < 4; ++rr) {
                int row = kgrp * 4 + rr;
                int off = (row * 128 + (((n3h * 16 + arow) * 2) ^ ((row & 7) << 4))) >> 1;
                mybA[off] = f2bf(gelu(a3A[n3h][rr] + bias));
                mybB[off] = f2bf(gelu(a3B[n3h][rr] + bias));
            }
        }
        #pragma unroll
        for (int k4 = 0; k4 < 2; ++k4) {
            int off = (arow * 128 + ((k4 * 64 + kgrp * 16) ^ ((arow & 7) << 4))) >> 1;
            bf16x8 afuA = *(const bf16x8*)(mybA + off);
            bf16x8 afuB = *(const bf16x8*)(mybB + off);
            #pragma unroll
            for (int n4 = 0; n4 < 8; ++n4) {
                bf16x8 bf = *(const bf16x8*)(sW4 + (size_t)(((n4 << 2) | (half * 2 + k4)) * 64 + lane) * 8);
                acc4A[n4] = __builtin_amdgcn_mfma_f32_16x16x32_bf16(afuA, bf, acc4A[n4], 0, 0, 0);
                acc4B[n4] = __builtin_amdgcn_mfma_f32_16x16x32_bf16(afuB, bf, acc4B[n4], 0, 0, 0);
            }
        }
    }
}

// ---- one sub-tile epilogue: stage rows in LDS -> 512B-contiguous stores
__device__ __forceinline__ void epilogue_tile(
    const f32x4 (&acc4)[8], float* mf, int arow, int kgrp, int q32, int c32,
    int row0s, int nrow, bool segA, int pos0, int c, int4 p8, int node, int g,
    const float* __restrict__ bu2, const ushort_t* __restrict__ bucket,
    float* __restrict__ out_g) {
    #pragma unroll
    for (int rr = 0; rr < 4; ++rr) {
        #pragma unroll
        for (int n4 = 0; n4 < 8; ++n4) {
            int col = n4 * 16 + arow;
            int blk = (col >> 2) ^ kgrp;
            mf[kgrp * 128 + blk * 4 + (col & 3)] = acc4[n4][rr] + bu2[col];
        }
        #pragma unroll
        for (int pair = 0; pair < 2; ++pair) {
            int slot = pair * 2 + q32;
            int src = slot * 4 + rr;
            bool valid = (row0s + src) < nrow;
            float4 val = *(const float4*)(mf + slot * 128 + ((c32 ^ slot) * 4));
            if (segA) {
                int p0v = __shfl(pos0, src);
                if (valid)
                    *(float4*)(out_g + (size_t)p0v * DD + c32 * 4) = val;
            } else {
                int c2 = __shfl(c, src);
                if (!valid) c2 = 0;
                unsigned u0 = (unsigned)__shfl(p8.x, src);
                unsigned u1 = (unsigned)__shfl(p8.y, src);
                unsigned u2 = (unsigned)__shfl(p8.z, src);
                unsigned u3 = (unsigned)__shfl(p8.w, src);
                if (c2 > 0) *(float4*)(out_g + (size_t)(u0 & 0xffff) * DD + c32 * 4) = val;
                if (c2 > 1) *(float4*)(out_g + (size_t)(u0 >> 16) * DD + c32 * 4) = val;
                if (c2 > 2) *(float4*)(out_g + (size_t)(u1 & 0xffff) * DD + c32 * 4) = val;
                if (c2 > 3) *(float4*)(out_g + (size_t)(u1 >> 16) * DD + c32 * 4) = val;
                if (__any(c2 > 4)) {
                    if (c2 > 4) *(float4*)(out_g + (size_t)(u2 & 0xffff) * DD + c32 * 4) = val;
                    if (c2 > 5) *(float4*)(out_g + (size_t)(u2 >> 16) * DD + c32 * 4) = val;
                    if (c2 > 6) *(float4*)(out_g + (size_t)(u3 & 0xffff) * DD + c32 * 4) = val;
                    if (c2 > 7) *(float4*)(out_g + (size_t)(u3 >> 16) * DD + c32 * 4) = val;
                }
                if (__any(c2 > 8)) {
                    int nd2 = __shfl(node, src);
                    const ushort_t* bt = bucket + ((size_t)nd2 * 8 + g) * 16;
                    for (int j = 8; j < 16; ++j) {
                        if (!__any(j < c2)) break;
                        if (j < c2)
                            *(float4*)(out_g + (size_t)bt[j] * DD + c32 * 4) = val;
                    }
                }
            }
        }
    }
}

#define GATHER_BASE(vv, posv, nodev)                                            \
    {                                                                           \
        const float* xp_ = x_g + (size_t)(posv) * DD + kgrp * 8;                \
        const float* bp_ = bd + (size_t)(nodev) * DD + kgrp * 8;                \
        _Pragma("unroll")                                                       \
        for (int ks = 0; ks < 4; ++ks) {                                        \
            float4 a0 = *(const float4*)(xp_ + ks * 32);                        \
            float4 a1 = *(const float4*)(xp_ + ks * 32 + 4);                    \
            float4 b0 = *(const float4*)(bp_ + ks * 32);                        \
            float4 b1 = *(const float4*)(bp_ + ks * 32 + 4);                    \
            vv[ks*8+0] = a0.x + b0.x; vv[ks*8+1] = a0.y + b0.y;                 \
            vv[ks*8+2] = a0.z + b0.z; vv[ks*8+3] = a0.w + b0.w;                 \
            vv[ks*8+4] = a1.x + b1.x; vv[ks*8+5] = a1.y + b1.y;                 \
            vv[ks*8+6] = a1.z + b1.z; vv[ks*8+7] = a1.w + b1.w;                 \
        }                                                                       \
    }

#define GATHER_EXTRA(vv, cv, p8v, nodev, posv)                                  \
    {                                                                           \
        const int pr1_ = ((unsigned)(p8v).x) >> 16;                             \
        const float* x1_ = x_g + (size_t)pr1_ * DD + kgrp * 8;                  \
        _Pragma("unroll")                                                       \
        for (int ks = 0; ks < 4; ++ks) {                                        \
            float4 d0 = *(const float4*)(x1_ + ks * 32);                        \
            float4 d1 = *(const float4*)(x1_ + ks * 32 + 4);                    \
            vv[ks*8+0] += d0.x; vv[ks*8+1] += d0.y;                             \
            vv[ks*8+2] += d0.z; vv[ks*8+3] += d0.w;                             \
            vv[ks*8+4] += d1.x; vv[ks*8+5] += d1.y;                             \
            vv[ks*8+6] += d1.z; vv[ks*8+7] += d1.w;                             \
        }                                                                       \
        if (__any((cv) > 2)) {                                                  \
            const int pr2_ = (p8v).y & 0xffff;                                  \
            const int pr3_ = ((unsigned)(p8v).y) >> 16;                         \
            const float* x2_ = x_g + (size_t)((cv) > 2 ? pr2_ : (posv)) * DD + kgrp * 8; \
            const float* x3_ = x_g + (size_t)((cv) > 3 ? pr3_ : (posv)) * DD + kgrp * 8; \
            const float m2_ = (cv) > 2 ? 1.f : 0.f;                             \
            const float m3_ = (cv) > 3 ? 1.f : 0.f;                             \
            _Pragma("unroll")                                                   \
            for (int ks = 0; ks < 4; ++ks) {                                    \
                float4 a0 = *(const float4*)(x2_ + ks * 32);                    \
                float4 a1 = *(const float4*)(x2_ + ks * 32 + 4);                \
                float4 d0 = *(const float4*)(x3_ + ks * 32);                    \
                float4 d1 = *(const float4*)(x3_ + ks * 32 + 4);                \
                vv[ks*8+0] = fmaf(m3_, d0.x, fmaf(m2_, a0.x, vv[ks*8+0]));      \
                vv[ks*8+1] = fmaf(m3_, d0.y, fmaf(m2_, a0.y, vv[ks*8+1]));      \
                vv[ks*8+2] = fmaf(m3_, d0.z, fmaf(m2_, a0.z, vv[ks*8+2]));      \
                vv[ks*8+3] = fmaf(m3_, d0.w, fmaf(m2_, a0.w, vv[ks*8+3]));      \
                vv[ks*8+4] = fmaf(m3_, d1.x, fmaf(m2_, a1.x, vv[ks*8+4]));      \
                vv[ks*8+5] = fmaf(m3_, d1.y, fmaf(m2_, a1.y, vv[ks*8+5]));      \
                vv[ks*8+6] = fmaf(m3_, d1.z, fmaf(m2_, a1.z, vv[ks*8+6]));      \
                vv[ks*8+7] = fmaf(m3_, d1.w, fmaf(m2_, a1.w, vv[ks*8+7]));      \
            }                                                                   \
        }                                                                       \
        if (__any((cv) > 4)) {                                                  \
            const ushort_t* bt_ = bucket + ((size_t)(nodev) * 8 + g) * 16;      \
            for (int j = 4; j < 16; j += 2) {                                   \
                if (!__any((cv) > j)) break;                                    \
                const int pa_ = (j < (cv)) ? bt_[j] : (posv);                   \
                const int pb_ = (j + 1 < (cv)) ? bt_[j + 1] : (posv);           \
                const float ma_ = (j < (cv)) ? 1.f : 0.f;                       \
                const float mb_ = (j + 1 < (cv)) ? 1.f : 0.f;                   \
                const float* xa_ = x_g + (size_t)pa_ * DD + kgrp * 8;           \
                const float* xb_ = x_g + (size_t)pb_ * DD + kgrp * 8;           \
                _Pragma("unroll")                                               \
                for (int ks = 0; ks < 4; ++ks) {                                \
                    float4 a0 = *(const float4*)(xa_ + ks * 32);                \
                    float4 a1 = *(const float4*)(xa_ + ks * 32 + 4);            \
                    float4 d0 = *(const float4*)(xb_ + ks * 32);                \
                    float4 d1 = *(const float4*)(xb_ + ks * 32 + 4);            \
                    vv[ks*8+0] = fmaf(mb_, d0.x, fmaf(ma_, a0.x, vv[ks*8+0]));  \
                    vv[ks*8+1] = fmaf(mb_, d0.y, fmaf(ma_, a0.y, vv[ks*8+1]));  \
                    vv[ks*8+2] = fmaf(mb_, d0.z, fmaf(ma_, a0.z, vv[ks*8+2]));  \
                    vv[ks*8+3] = fmaf(mb_, d0.w, fmaf(ma_, a0.w, vv[ks*8+3]));  \
                    vv[ks*8+4] = fmaf(mb_, d1.x, fmaf(ma_, a1.x, vv[ks*8+4]));  \
                    vv[ks*8+5] = fmaf(mb_, d1.y, fmaf(ma_, a1.y, vv[ks*8+5]));  \
                    vv[ks*8+6] = fmaf(mb_, d1.z, fmaf(ma_, a1.z, vv[ks*8+6]));  \
                    vv[ks*8+7] = fmaf(mb_, d1.w, fmaf(ma_, a1.w, vv[ks*8+7]));  \
                }                                                               \
            }                                                                   \
        }                                                                       \
    }

// ---- fused kernel: 2 independent 16-row sub-tiles per wave (ILP x2),
// weight LDS reads shared between the pair. 512 threads = 8 waves.
// LDS: W1 64K + W2 32K + W4 32K + 8x4K buffers = 160KB exactly; W3 from L2.
__global__ __launch_bounds__(512, 2) void fused_kernel(
    const float* __restrict__ x, const float* __restrict__ bd,
    const float* __restrict__ lndg, const float* __restrict__ lndb,
    const short* __restrict__ pW1, const short* __restrict__ pW2,
    const short* __restrict__ pW3, const short* __restrict__ pW4,
    const float* __restrict__ bd1, const float* __restrict__ bd2,
    const float* __restrict__ lnug, const float* __restrict__ lnub,
    const float* __restrict__ bu1, const float* __restrict__ bu2,
    const int2* __restrict__ list1, const int* __restrict__ cnts1,
    const int* __restrict__ list2, const int* __restrict__ cnts2,
    const int* __restrict__ pernode, const ushort_t* __restrict__ bucket,
    float* __restrict__ out) {
    __shared__ short sW1[4096 * 8];
    __shared__ short sW2[2048 * 8];
    __shared__ short sW4[2048 * 8];
    __shared__ short sBuf[8][2048];

    const int tid = threadIdx.x;
    for (int s = tid; s < 4096; s += 512)
        *(bf16x8*)(sW1 + s * 8) = *(const bf16x8*)(pW1 + (size_t)s * 8);
    for (int s = tid; s < 2048; s += 512)
        *(bf16x8*)(sW2 + s * 8) = *(const bf16x8*)(pW2 + (size_t)s * 8);
    for (int s = tid; s < 2048; s += 512)
        *(bf16x8*)(sW4 + s * 8) = *(const bf16x8*)(pW4 + (size_t)s * 8);
    __syncthreads();

    const int wave = tid >> 6, lane = tid & 63;
    short* mybA = sBuf[wave];
    short* mybB = sBuf[wave] + 1024;
    const int arow = lane & 15;
    const int kgrp = lane >> 4;
    const int q32 = lane >> 5, c32 = lane & 31;

    for (int w = blockIdx.x; w < T1MAX + T2MAX; w += gridDim.x) {
        const bool segA = w < T1MAX;
        int g, row0, nrow;
        if (segA) {
            g = w & 7; row0 = (w >> 3) * 256 + wave * 32; nrow = cnts1[g];
        } else {
            int w2 = w - T1MAX;
            g = w2 & 7; row0 = (w2 >> 3) * 256 + wave * 32; nrow = cnts2[g];
        }
        if (row0 >= nrow) continue;
        const float* x_g = x + (size_t)g * NS * DD;
        float* out_g = out + (size_t)g * NS * DD;
        const int giA = row0 + arow;
        const int giB = row0 + 16 + arow;
        const int gidxA = giA < nrow ? giA : nrow - 1;
        const int gidxB = giB < nrow ? giB : nrow - 1;

        int nodeA, cA = 1, posA;
        int nodeB, cB = 1, posB;
        int4 p8A = (int4){0, 0, 0, 0};
        int4 p8B = (int4){0, 0, 0, 0};
        if (segA) {
            int2 pa = list1[(size_t)g * NS + gidxA];
            int2 pb = list1[(size_t)g * NS + gidxB];
            posA = pa.x; nodeA = pa.y;
            posB = pb.x; nodeB = pb.y;
        } else {
            nodeA = list2[(size_t)g * L2CAP + gidxA];
            nodeB = list2[(size_t)g * L2CAP + gidxB];
            cA = pernode[nodeA * 8 + g];
            cB = pernode[nodeB * 8 + g];
            p8A = *(const int4*)(bucket + ((size_t)nodeA * 8 + g) * 16);
            p8B = *(const int4*)(bucket + ((size_t)nodeB * 8 + g) * 16);
            posA = p8A.x & 0xffff;
            posB = p8B.x & 0xffff;
        }

        float va[32], vb[32];
        GATHER_BASE(va, posA, nodeA);
        GATHER_BASE(vb, posB, nodeB);
        if (!segA) {
            GATHER_EXTRA(va, cA, p8A, nodeA, posA);
            GATHER_EXTRA(vb, cB, p8B, nodeB, posB);
        }

        bf16x8 afrA[4], afrB[4];
        ln_d_pack(va, kgrp, lndg, lndb, afrA);
        ln_d_pack(vb, kgrp, lndg, lndb, afrB);

        f32x4 acc4A[8], acc4B[8];
        mlp_core2(afrA, afrB, mybA, mybB, arow, kgrp, sW1, sW2, pW3, sW4,
                  bd1, bd2, lnug, lnub, bu1, acc4A, acc4B);

        epilogue_tile(acc4A, (float*)mybA, arow, kgrp, q32, c32, row0, nrow,
                      segA, posA, cA, p8A, nodeA, g, bu2, bucket, out_g);
        epilogue_tile(acc4B, (float*)mybB, arow, kgrp, q32, c32, row0 + 16, nrow,
                      segA, posB, cB, p8B, nodeB, g, bu2, bucket, out_g);
    }
}

extern "C" void kernel_launch(void* const* d_in, const int* in_sizes, int n_in,
                              void* d_out, int out_size, void* d_ws, size_t ws_size,
                              hipStream_t stream) {
    const float* x       = (const float*)d_in[0];
    const int*   indices = (const int*)d_in[1];
    const float* bd      = (const float*)d_in[2];
    const float* ln_d_g  = (const float*)d_in[3];
    const float* ln_d_b  = (const float*)d_in[4];
    const float* Wd1     = (const float*)d_in[5];
    const float* bd1     = (const float*)d_in[6];
    const float* Wd2     = (const float*)d_in[7];
    const float* bd2     = (const float*)d_in[8];
    const float* ln_u_g  = (const float*)d_in[9];
    const float* ln_u_b  = (const float*)d_in[10];
    const float* Wu1     = (const float*)d_in[11];
    const float* bu1     = (const float*)d_in[12];
    const float* Wu2     = (const float*)d_in[13];
    const float* bu2     = (const float*)d_in[14];
    float* out = (float*)d_out;

    char* ws = (char*)d_ws;
    size_t o = 0;
    auto alloc_b = [&](size_t bytes) { char* p = ws + o; o = (o + bytes + 255) & ~(size_t)255; return p; };
    // pernode + cnts1 + cnts2 contiguous -> zeroed by prep_all
    int*      pernode = (int*)alloc_b((size_t)NN * 8 * 4);
    int*      cnts1   = (int*)alloc_b(8 * 4);
    int*      cnts2   = (int*)alloc_b(8 * 4);
    int2*     list1   = (int2*)alloc_b((size_t)8 * NS * 8);
    int*      list2   = (int*)alloc_b((size_t)8 * L2CAP * 4);
    ushort_t* bucket  = (ushort_t*)alloc_b((size_t)NN * 8 * 16 * 2);
    short*    pW1     = (short*)alloc_b((size_t)4096 * 16);
    short*    pW2     = (short*)alloc_b((size_t)2048 * 16);
    short*    pW3     = (short*)alloc_b((size_t)1024 * 16);
    short*    pW4     = (short*)alloc_b((size_t)2048 * 16);

    prep_all<<<36 + (ZINT4 + 255) / 256, 256, 0, stream>>>(Wd1, Wd2, Wu1, Wu2,
                                                           pW1, pW2, pW3, pW4,
                                                           (int4*)pernode);
    flagfill_kernel<<<(G8 * NS + 255) / 256, 256, 0, stream>>>(indices, pernode, bucket);
    compact2_kernel<<<dim3((NN + 255) / 256, G8), 256, 0, stream>>>(indices, pernode,
                                                                    list1, cnts1,
                                                                    list2, cnts2);
    fused_kernel<<<256, 512, 0, stream>>>(x, bd, ln_d_g, ln_d_b,
                                          pW1, pW2, pW3, pW4,
                                          bd1, bd2, ln_u_g, ln_u_b, bu1, bu2,
                                          list1, cnts1, list2, cnts2,
                                          pernode, bucket, out);
}